// Round 7
// baseline (46.598 us; speedup 1.0000x reference)
//
#include <hip/hip_runtime.h>

#define N1 8192
#define N2 8192
#define KNN 32

// f32(0.1*0.1) -- the reference's weak-promoted threshold (bit-exact vs np ref, round 2)
#define R2_F32 0.009999999776482582f

struct F3 { float x, y, z; };

__device__ __forceinline__ F3 ld3(const float* __restrict__ p, int j) {
    // 12 contiguous bytes per lane -> LLVM merges to global_load_dwordx3
    F3 r;
    r.x = p[3 * j + 0];
    r.y = p[3 * j + 1];
    r.z = p[3 * j + 2];
    return r;
}

__global__ __launch_bounds__(256) void ballq_kernel(
    const float* __restrict__ p1, const float* __restrict__ p2,
    float* __restrict__ map_f, float* __restrict__ cnt_f, float* __restrict__ out_f)
{
    const int q    = (int)((blockIdx.x * blockDim.x + threadIdx.x) >> 6); // one wave per query
    const int lane = (int)(threadIdx.x & 63);
    if (q >= N1) return;

    const float qx = p1[3 * q + 0];
    const float qy = p1[3 * q + 1];
    const float qz = p1[3 * q + 2];
    // s1 = (qx^2 + qy^2) + qz^2 -- numpy style: rounded muls, sequential adds, no FMA
    const float s1 = __fadd_rn(__fadd_rn(__fmul_rn(qx, qx), __fmul_rn(qy, qy)),
                               __fmul_rn(qz, qz));

    const unsigned long long lt_mask = (1ull << lane) - 1ull;
    const int base_map = q * KNN;
    int count = 0;  // accumulates TOTAL within-count; slot writes guarded by pos<KNN

    // Bit-exact classification (do not change): f32 gram trick as numpy computes it.
    auto process = [&](const F3& pp, int jbase) {
        const int j = jbase + lane;
        const float s2 = __fadd_rn(__fadd_rn(__fmul_rn(pp.x, pp.x), __fmul_rn(pp.y, pp.y)),
                                   __fmul_rn(pp.z, pp.z));
        const float dot = __fmaf_rn(qz, pp.z, __fmaf_rn(qy, pp.y, __fmul_rn(qx, pp.x)));
        const float d2 = __fsub_rn(__fadd_rn(s1, s2), __fadd_rn(dot, dot));
        const bool within = (d2 <= R2_F32);
        const unsigned long long mask = __ballot(within);
        const int pos = count + (int)__popcll(mask & lt_mask);
        if (within && pos < KNN) {
            map_f[base_map + pos] = (float)j;
            float* o = out_f + (size_t)(base_map + pos) * 3;
            o[0] = pp.x; o[1] = pp.y; o[2] = pp.z;
        }
        count += (int)__popcll(mask);
    };

    // 4-chunk-deep software pipeline over 128 chunks of 64 candidates.
    // No early exit: E[neighbors]~30 means most waves scan everything anyway;
    // removing the break makes the loop branch-free so loads stay in flight.
    constexpr int NMB = N2 / 256;  // 32 macro-iterations of 4 chunks
    F3 b0 = ld3(p2, 0 * 64 + lane);
    F3 b1 = ld3(p2, 1 * 64 + lane);
    F3 b2 = ld3(p2, 2 * 64 + lane);
    F3 b3 = ld3(p2, 3 * 64 + lane);

    for (int mb = 0; mb < NMB; ++mb) {
        const int nb = (mb + 1 < NMB) ? (mb + 1) : 0;  // last prefetch wraps to 0 (harmless)
        F3 n0 = ld3(p2, nb * 256 + 0 * 64 + lane);
        F3 n1 = ld3(p2, nb * 256 + 1 * 64 + lane);
        F3 n2 = ld3(p2, nb * 256 + 2 * 64 + lane);
        F3 n3 = ld3(p2, nb * 256 + 3 * 64 + lane);

        const int jb = mb * 256;
        process(b0, jb + 0 * 64);
        process(b1, jb + 1 * 64);
        process(b2, jb + 2 * 64);
        process(b3, jb + 3 * 64);

        b0 = n0; b1 = n1; b2 = n2; b3 = n3;
    }

    if (count > KNN) count = KNN;

    // Zero-fill the padded tail (d_out is poisoned; every element must be written)
    if (lane < KNN - count) {
        const int s = base_map + count + lane;
        map_f[s] = 0.0f;
        float* o = out_f + (size_t)s * 3;
        o[0] = 0.0f; o[1] = 0.0f; o[2] = 0.0f;
    }
    if (lane == 0) cnt_f[q] = (float)count;
}

extern "C" void kernel_launch(void* const* d_in, const int* in_sizes, int n_in,
                              void* d_out, int out_size, void* d_ws, size_t ws_size,
                              hipStream_t stream) {
    const float* p1 = (const float*)d_in[0];  // [1, N1, 3] f32
    const float* p2 = (const float*)d_in[1];  // [1, N2, 3] f32
    float* out = (float*)d_out;

    float* map_f = out;                        // N1*KNN (mapping as float)
    float* cnt_f = out + (size_t)N1 * KNN;     // N1 (counts as float)
    float* out_f = cnt_f + N1;                 // N1*KNN*3 (gathered coords)

    dim3 block(256);
    dim3 grid(N1 / (256 / 64));  // one wave per query
    hipLaunchKernelGGL(ballq_kernel, grid, block, 0, stream,
                       p1, p2, map_f, cnt_f, out_f);
}

// Round 8
// 37.922 us; speedup vs baseline: 1.2288x; 1.2288x over previous
//
#include <hip/hip_runtime.h>

#define N1 8192
#define N2 8192
#define KNN 32
#define QPW 4   // queries per wave

// f32(0.1*0.1) -- the reference's weak-promoted threshold (bit-exact vs np ref, rounds 2/7)
#define R2_F32 0.009999999776482582f

struct F3 { float x, y, z; };

__device__ __forceinline__ F3 ld3(const float* __restrict__ p, int j) {
    // 12 contiguous bytes per lane -> global_load_dwordx3
    F3 r;
    r.x = p[3 * j + 0];
    r.y = p[3 * j + 1];
    r.z = p[3 * j + 2];
    return r;
}

// popcount(mask & lanemask_lt) in 2 VALU instrs
__device__ __forceinline__ int prefix_lt(unsigned long long m) {
    return (int)__builtin_amdgcn_mbcnt_hi(
        (unsigned)(m >> 32),
        __builtin_amdgcn_mbcnt_lo((unsigned)m, 0u));
}

__global__ __launch_bounds__(256) void ballq_kernel(
    const float* __restrict__ p1, const float* __restrict__ p2,
    float* __restrict__ map_f, float* __restrict__ cnt_f, float* __restrict__ out_f)
{
    const int w    = (int)((blockIdx.x * blockDim.x + threadIdx.x) >> 6); // wave id
    const int lane = (int)(threadIdx.x & 63);
    const int q0   = w * QPW;                      // this wave's 4 queries
    if (q0 >= N1) return;

    float qx[QPW], qy[QPW], qz[QPW], s1[QPW];
#pragma unroll
    for (int i = 0; i < QPW; ++i) {
        qx[i] = p1[3 * (q0 + i) + 0];
        qy[i] = p1[3 * (q0 + i) + 1];
        qz[i] = p1[3 * (q0 + i) + 2];
        // numpy style: rounded muls, sequential adds, no FMA (bit-exact, do not change)
        s1[i] = __fadd_rn(__fadd_rn(__fmul_rn(qx[i], qx[i]), __fmul_rn(qy[i], qy[i])),
                          __fmul_rn(qz[i], qz[i]));
    }

    int count[QPW] = {0, 0, 0, 0};  // wave-uniform totals (clamped at the end)

    // Bit-exact per-pair classification (do not change): f32 gram trick as numpy computes it.
    // s2 is query-independent -> computed once, shared by all QPW queries.
    auto process = [&](const F3& pp, int jbase) {
        const int j = jbase + lane;
        const float s2 = __fadd_rn(__fadd_rn(__fmul_rn(pp.x, pp.x), __fmul_rn(pp.y, pp.y)),
                                   __fmul_rn(pp.z, pp.z));
#pragma unroll
        for (int i = 0; i < QPW; ++i) {
            const float dot = __fmaf_rn(qz[i], pp.z, __fmaf_rn(qy[i], pp.y, __fmul_rn(qx[i], pp.x)));
            const float d2  = __fsub_rn(__fadd_rn(s1[i], s2), __fadd_rn(dot, dot));
            const bool within = (d2 <= R2_F32);
            const unsigned long long mask = __ballot(within);
            if (mask) {  // scalar branch, ~82% skip rate per query
                const int pos = count[i] + prefix_lt(mask);
                if (within && pos < KNN) {
                    const int s = (q0 + i) * KNN + pos;   // int offsets: no 64-bit addr math
                    map_f[s] = (float)j;
                    float* o = out_f + s * 3;
                    o[0] = pp.x; o[1] = pp.y; o[2] = pp.z;
                }
                count[i] += (int)__popcll(mask);
            }
        }
    };

    // 4-chunk-deep register pipeline over 128 chunks of 64 candidates.
    // Macro body is branchless; early exit only at macro granularity (uniform
    // scalar check) so next-macro loads are already in flight.
    constexpr int NMB = N2 / 256;  // 32 macro-iterations
    F3 b0 = ld3(p2, 0 * 64 + lane);
    F3 b1 = ld3(p2, 1 * 64 + lane);
    F3 b2 = ld3(p2, 2 * 64 + lane);
    F3 b3 = ld3(p2, 3 * 64 + lane);

    for (int mb = 0; mb < NMB; ++mb) {
        const int nb = (mb + 1 < NMB) ? (mb + 1) : 0;  // wrap prefetch (harmless)
        F3 n0 = ld3(p2, nb * 256 + 0 * 64 + lane);
        F3 n1 = ld3(p2, nb * 256 + 1 * 64 + lane);
        F3 n2 = ld3(p2, nb * 256 + 2 * 64 + lane);
        F3 n3 = ld3(p2, nb * 256 + 3 * 64 + lane);

        const int jb = mb * 256;
        process(b0, jb + 0 * 64);
        process(b1, jb + 1 * 64);
        process(b2, jb + 2 * 64);
        process(b3, jb + 3 * 64);

        b0 = n0; b1 = n1; b2 = n2; b3 = n3;

        if (count[0] >= KNN && count[1] >= KNN && count[2] >= KNN && count[3] >= KNN)
            break;
    }

#pragma unroll
    for (int i = 0; i < QPW; ++i) {
        int c = count[i] > KNN ? KNN : count[i];
        // Zero-fill padded tail (d_out is poisoned; every element must be written)
        if (lane < KNN - c) {
            const int s = (q0 + i) * KNN + c + lane;
            map_f[s] = 0.0f;
            float* o = out_f + s * 3;
            o[0] = 0.0f; o[1] = 0.0f; o[2] = 0.0f;
        }
        if (lane == 0) cnt_f[q0 + i] = (float)c;
    }
}

extern "C" void kernel_launch(void* const* d_in, const int* in_sizes, int n_in,
                              void* d_out, int out_size, void* d_ws, size_t ws_size,
                              hipStream_t stream) {
    const float* p1 = (const float*)d_in[0];  // [1, N1, 3] f32
    const float* p2 = (const float*)d_in[1];  // [1, N2, 3] f32
    float* out = (float*)d_out;

    float* map_f = out;                        // N1*KNN (mapping as float)
    float* cnt_f = out + (size_t)N1 * KNN;     // N1 (counts as float)
    float* out_f = cnt_f + N1;                 // N1*KNN*3 (gathered coords)

    const int waves = N1 / QPW;                // 2048 waves
    dim3 block(256);                           // 4 waves/block
    dim3 grid(waves / 4);                      // 512 blocks
    hipLaunchKernelGGL(ballq_kernel, grid, block, 0, stream,
                       p1, p2, map_f, cnt_f, out_f);
}

// Round 10
// 25.517 us; speedup vs baseline: 1.8261x; 1.4861x over previous
//
#include <hip/hip_runtime.h>

#define N1 8192
#define N2 8192
#define KNN 32
#define QPW 4                 // queries per wave (block = 1 query group)
#define NSPLIT 4              // candidate slices (= waves per block)
#define SLICE (N2 / NSPLIT)   // 2048 candidates per wave

// f32(0.1*0.1) -- the reference's weak-promoted threshold (bit-exact vs np ref, rounds 2/7/8)
#define R2_F32 0.009999999776482582f

struct F3 { float x, y, z; };

__device__ __forceinline__ F3 ld3(const float* __restrict__ p, int j) {
    F3 r;
    r.x = p[3 * j + 0];
    r.y = p[3 * j + 1];
    r.z = p[3 * j + 2];
    return r;
}

// popcount(mask & lanemask_lt) in 2 VALU instrs
__device__ __forceinline__ int prefix_lt(unsigned long long m) {
    return (int)__builtin_amdgcn_mbcnt_hi(
        (unsigned)(m >> 32),
        __builtin_amdgcn_mbcnt_lo((unsigned)m, 0u));
}

__global__ __launch_bounds__(256, 8) void ballq_kernel(
    const float* __restrict__ p1, const float* __restrict__ p2,
    float* __restrict__ map_f, float* __restrict__ cnt_f, float* __restrict__ out_f)
{
    // Per-wave hit buffers: slot order within a slice == index order.
    __shared__ float4 buf[NSPLIT][QPW][KNN];   // 8 KB
    __shared__ int    cnts[NSPLIT][QPW];       // uncapped per-slice totals

    const int g    = (int)blockIdx.x;          // query group
    const int h    = (int)(threadIdx.x >> 6);  // slice id 0..3 (wave in block)
    const int lane = (int)(threadIdx.x & 63);
    const int q0   = g * QPW;

    float qx[QPW], qy[QPW], qz[QPW], s1[QPW];
#pragma unroll
    for (int i = 0; i < QPW; ++i) {
        qx[i] = p1[3 * (q0 + i) + 0];
        qy[i] = p1[3 * (q0 + i) + 1];
        qz[i] = p1[3 * (q0 + i) + 2];
        // numpy style: rounded muls, sequential adds, no FMA (bit-exact, do not change)
        s1[i] = __fadd_rn(__fadd_rn(__fmul_rn(qx[i], qx[i]), __fmul_rn(qy[i], qy[i])),
                          __fmul_rn(qz[i], qz[i]));
    }

    int count[QPW] = {0, 0, 0, 0};
    const int jofs = h * SLICE;

    // Bit-exact per-pair classification (do not change): f32 gram trick as numpy
    // computes it. s2 is query-independent -> shared by all QPW queries.
    auto process = [&](const F3& pp, int jbase) {
        const int j = jbase + lane;
        const float s2 = __fadd_rn(__fadd_rn(__fmul_rn(pp.x, pp.x), __fmul_rn(pp.y, pp.y)),
                                   __fmul_rn(pp.z, pp.z));
#pragma unroll
        for (int i = 0; i < QPW; ++i) {
            const float dot = __fmaf_rn(qz[i], pp.z, __fmaf_rn(qy[i], pp.y, __fmul_rn(qx[i], pp.x)));
            const float d2  = __fsub_rn(__fadd_rn(s1[i], s2), __fadd_rn(dot, dot));
            const bool within = (d2 <= R2_F32);
            const unsigned long long mask = __ballot(within);
            if (mask) {  // scalar skip, ~80% of query-chunks
                const int pos = count[i] + prefix_lt(mask);
                if (within && pos < KNN)
                    buf[h][i][pos] = make_float4((float)j, pp.x, pp.y, pp.z);
                count[i] += (int)__popcll(mask);
            }
        }
    };

    // 4-chunk-deep register pipeline over this wave's 32 chunks of 64.
    constexpr int NMB = SLICE / 256;  // 8 macro-iterations
    F3 b0 = ld3(p2, jofs + 0 * 64 + lane);
    F3 b1 = ld3(p2, jofs + 1 * 64 + lane);
    F3 b2 = ld3(p2, jofs + 2 * 64 + lane);
    F3 b3 = ld3(p2, jofs + 3 * 64 + lane);

    for (int mb = 0; mb < NMB; ++mb) {
        const int nb = (mb + 1 < NMB) ? (mb + 1) : 0;  // wrap prefetch (harmless)
        F3 n0 = ld3(p2, jofs + nb * 256 + 0 * 64 + lane);
        F3 n1 = ld3(p2, jofs + nb * 256 + 1 * 64 + lane);
        F3 n2 = ld3(p2, jofs + nb * 256 + 2 * 64 + lane);
        F3 n3 = ld3(p2, jofs + nb * 256 + 3 * 64 + lane);

        const int jb = jofs + mb * 256;
        process(b0, jb + 0 * 64);
        process(b1, jb + 1 * 64);
        process(b2, jb + 2 * 64);
        process(b3, jb + 3 * 64);

        b0 = n0; b1 = n1; b2 = n2; b3 = n3;
        // no early exit: all waves must reach the barrier
    }

    if (lane == 0) {
        cnts[h][0] = count[0];
        cnts[h][1] = count[1];
        cnts[h][2] = count[2];
        cnts[h][3] = count[3];
    }
    __syncthreads();

    // Merge: wave h copies its slots to [start_h, start_h + n_h); disjoint ranges,
    // globally index-ordered. Wave 0 also zero-fills the tail and writes counts.
#pragma unroll
    for (int i = 0; i < QPW; ++i) {
        const int c0 = cnts[0][i];
        const int c1 = cnts[1][i];
        const int c2 = cnts[2][i];
        const int c3 = cnts[3][i];

        int pref = 0;
        if (h > 0) pref += c0;
        if (h > 1) pref += c1;
        if (h > 2) pref += c2;
        int start = pref < KNN ? pref : KNN;
        const int ch = cnts[h][i];
        int nh = KNN - start;
        if (ch < nh) nh = ch;

        if (lane < nh) {
            const float4 f = buf[h][i][lane];
            const int s = (q0 + i) * KNN + start + lane;
            map_f[s] = f.x;
            float* o = out_f + s * 3;
            o[0] = f.y; o[1] = f.z; o[2] = f.w;
        }

        if (h == 0) {
            int total = c0 + c1 + c2 + c3;
            if (total > KNN) total = KNN;
            if (lane < KNN - total) {
                const int s = (q0 + i) * KNN + total + lane;
                map_f[s] = 0.0f;
                float* o = out_f + s * 3;
                o[0] = 0.0f; o[1] = 0.0f; o[2] = 0.0f;
            }
            if (lane == 0) cnt_f[q0 + i] = (float)total;
        }
    }
}

extern "C" void kernel_launch(void* const* d_in, const int* in_sizes, int n_in,
                              void* d_out, int out_size, void* d_ws, size_t ws_size,
                              hipStream_t stream) {
    const float* p1 = (const float*)d_in[0];  // [1, N1, 3] f32
    const float* p2 = (const float*)d_in[1];  // [1, N2, 3] f32
    float* out = (float*)d_out;

    float* map_f = out;                        // N1*KNN (mapping as float)
    float* cnt_f = out + (size_t)N1 * KNN;     // N1 (counts as float)
    float* out_f = cnt_f + N1;                 // N1*KNN*3 (gathered coords)

    dim3 block(256);                           // 4 waves = 4 candidate slices
    dim3 grid(N1 / QPW);                       // 2048 blocks, one query group each
    hipLaunchKernelGGL(ballq_kernel, grid, block, 0, stream,
                       p1, p2, map_f, cnt_f, out_f);
}